// Round 16
// baseline (474.535 us; speedup 1.0000x reference)
//
#include <hip/hip_runtime.h>
#include <hip/hip_fp16.h>
#include <cstddef>

// ---------------------------------------------------------------------------
// CrystalGNN (SchNet-style). R24 = R23 resubmitted (R15-round infra failure).
//   Theory: gather is L2-thrash latency bound (h = 6.4MB > 4MB/XCD L2,
//   ~50% hit). Split each gather into TWO time-separated passes over
//   feature halves: pass touches only 64B of each 128B h row -> 3.2MB
//   working set < 4MB L2 (if 64B lines) -> near-resident.
//   k_gatherh: lanes 0-31 = even edges, 32-63 = odd edges, features
//   f0+(lane&31); per-node loop wave-uniform; halves combined via
//   __shfl_xor(acc,32); lanes 0-31 write agg[n][f0..f0+32).
//   Costs: psort read x2 (+12.8MB ~ 2us), +3 launches. Everything else
//   identical to R22/R20 (measured best 379-380us).
//   fallback (ws too small): R8 fused k_conv + one-pass scatter.
// ---------------------------------------------------------------------------

#define BSH 8   // 256 nodes per scatter bucket

// C_r = exp(-0.5 r^2), r = 0..9
#define RBF_C0 1.0f
#define RBF_C1 0.60653065971f
#define RBF_C2 0.13533528324f
#define RBF_C3 0.011108996538f
#define RBF_C4 3.3546262790e-4f
#define RBF_C5 3.7266531720e-6f
#define RBF_C6 1.5229979745e-8f
#define RBF_C7 2.2897348457e-11f
#define RBF_C8 1.2664165549e-14f
#define RBF_C9 2.5767043600e-18f

__device__ __forceinline__ float softplusf(float v) {
    return fmaxf(v, 0.0f) + log1pf(__expf(-fabsf(v)));
}

__device__ __forceinline__ float row_gemv(const float4* __restrict__ xr,
                                          const float w[64], float bj) {
    float a0 = bj, a1 = 0.f, a2 = 0.f, a3 = 0.f;
#pragma unroll
    for (int q = 0; q < 4; ++q) {
        float4 v0 = xr[4 * q + 0], v1 = xr[4 * q + 1];
        float4 v2 = xr[4 * q + 2], v3 = xr[4 * q + 3];
        a0 = fmaf(v0.x, w[16 * q + 0], a0);  a0 = fmaf(v0.y, w[16 * q + 1], a0);
        a0 = fmaf(v0.z, w[16 * q + 2], a0);  a0 = fmaf(v0.w, w[16 * q + 3], a0);
        a1 = fmaf(v1.x, w[16 * q + 4], a1);  a1 = fmaf(v1.y, w[16 * q + 5], a1);
        a1 = fmaf(v1.z, w[16 * q + 6], a1);  a1 = fmaf(v1.w, w[16 * q + 7], a1);
        a2 = fmaf(v2.x, w[16 * q + 8], a2);  a2 = fmaf(v2.y, w[16 * q + 9], a2);
        a2 = fmaf(v2.z, w[16 * q + 10], a2); a2 = fmaf(v2.w, w[16 * q + 11], a2);
        a3 = fmaf(v3.x, w[16 * q + 12], a3); a3 = fmaf(v3.y, w[16 * q + 13], a3);
        a3 = fmaf(v3.z, w[16 * q + 14], a3); a3 = fmaf(v3.w, w[16 * q + 15], a3);
    }
    return (a0 + a1) + (a2 + a3);
}

__device__ __forceinline__ float filt_ab(const float wp[10], float bj, float A, float B) {
    float P = wp[9];
    P = fmaf(B, P, wp[8]); P = fmaf(B, P, wp[7]); P = fmaf(B, P, wp[6]);
    P = fmaf(B, P, wp[5]); P = fmaf(B, P, wp[4]); P = fmaf(B, P, wp[3]);
    P = fmaf(B, P, wp[2]); P = fmaf(B, P, wp[1]); P = fmaf(B, P, wp[0]);
    return fmaf(A, P, bj);
}

// ---------------- hist + gstart + embed + gemm0 (independent passes) -------
__global__ void k_pre(const int* __restrict__ dst, int* __restrict__ deg,
                      const int* __restrict__ batch, int* __restrict__ gstart,
                      const int* __restrict__ ids, const float* __restrict__ emb,
                      const float* __restrict__ W1, const float* __restrict__ b1,
                      float* __restrict__ x, __half* __restrict__ hA,
                      int n_edges, int n_nodes, int n_graphs) {
    int tid = blockIdx.x * blockDim.x + threadIdx.x;
    int nth = gridDim.x * blockDim.x;
    for (int e = tid; e < n_edges; e += nth) atomicAdd(&deg[dst[e]], 1);
    for (int n = tid; n < n_nodes; n += nth) {
        int b = batch[n];
        int prev = (n == 0) ? -1 : batch[n - 1];
        for (int g = prev + 1; g <= b; ++g) gstart[g] = n;
        if (n == n_nodes - 1)
            for (int g = b + 1; g <= n_graphs; ++g) gstart[g] = n_nodes;
    }
    // gemm0: x = emb[ids], hA = x @ W1[0] + b1[0]
    int lane = threadIdx.x & 63;
    int gw = __builtin_amdgcn_readfirstlane(tid >> 6);
    int nw = nth >> 6;
    float w[64];
#pragma unroll
    for (int k = 0; k < 64; ++k) w[k] = W1[k * 64 + lane];
    float bj = b1[lane];
    for (int n = gw; n < n_nodes; n += nw) {
        int id = __builtin_amdgcn_readfirstlane(ids[n]);
        const float4* xr = (const float4*)(emb + id * 64);
        float v = row_gemv(xr, w, bj);
        x[n * 64 + lane] = emb[id * 64 + lane];
        hA[n * 64 + lane] = __float2half(v);
    }
}

// ---------------- scan ----------------
__global__ void k_scana(const int* __restrict__ deg, int* __restrict__ off_,
                        int* __restrict__ bsum, int n) {
    __shared__ int s[256];
    int i = blockIdx.x * 256 + threadIdx.x;
    int v = (i < n) ? deg[i] : 0;
    s[threadIdx.x] = v;
    __syncthreads();
    for (int off = 1; off < 256; off <<= 1) {
        int t = (threadIdx.x >= off) ? s[threadIdx.x - off] : 0;
        __syncthreads();
        s[threadIdx.x] += t;
        __syncthreads();
    }
    if (i < n) off_[i + 1] = s[threadIdx.x];
    if (threadIdx.x == 255) bsum[blockIdx.x] = s[255];
}

__global__ void k_scanb(int* __restrict__ bsum, int nb) {
    __shared__ int s[256];
    int v = ((int)threadIdx.x < nb) ? bsum[threadIdx.x] : 0;
    s[threadIdx.x] = v;
    __syncthreads();
    for (int off = 1; off < 256; off <<= 1) {
        int t = (threadIdx.x >= off) ? s[threadIdx.x - off] : 0;
        __syncthreads();
        s[threadIdx.x] += t;
        __syncthreads();
    }
    if ((int)threadIdx.x < nb) bsum[threadIdx.x] = s[threadIdx.x] - v;  // exclusive
}

__global__ void k_scanc(const int* __restrict__ deg, const int* __restrict__ bsum,
                        int* __restrict__ off_, int* __restrict__ cursor,
                        int* __restrict__ bcursor, int n) {
    int i = blockIdx.x * blockDim.x + threadIdx.x;
    if (i < n) {
        int incl = off_[i + 1] + bsum[i >> 8];
        off_[i + 1] = incl;
        cursor[i] = incl - deg[i];
        // bucket start: bcursor[b] = off_[b<<BSH]
        if (((i + 1) & ((1 << BSH) - 1)) == 0)
            bcursor[(i + 1) >> BSH] = incl;
    }
    if (i == 0) { off_[0] = 0; bcursor[0] = 0; }
}

// ---------------- scatter pass 1: LDS counting-sort into bucket runs -------
__global__ __launch_bounds__(256) void k_scat1(
        const int* __restrict__ src, const int* __restrict__ dst,
        const float* __restrict__ dist, int* __restrict__ bcursor,
        int4* __restrict__ tmp, int n_edges) {
    __shared__ int hist[256], sofs[256], hbase[256], lcur[256];
    __shared__ int4 buf[1024];
    const int t = threadIdx.x;
    const int base = blockIdx.x << 10;

    hist[t] = 0;
    __syncthreads();

    int bk[4]; int4 pl[4];
#pragma unroll
    for (int i = 0; i < 4; ++i) {
        int e = base + (i << 8) + t;
        if (e < n_edges) {
            int d_ = dst[e];
            float dd = dist[e];
            float A = __expf(-1.125f * dd * dd);
            float B = __expf(1.5f * dd);
            pl[i] = make_int4(src[e] << 6, __float_as_int(A), __float_as_int(B), d_);
            bk[i] = d_ >> BSH;
            atomicAdd(&hist[bk[i]], 1);
        } else bk[i] = -1;
    }
    __syncthreads();

    int mycnt = hist[t];
    // inclusive Hillis-Steele scan over 256 entries
    for (int off = 1; off < 256; off <<= 1) {
        int v = (t >= off) ? hist[t - off] : 0;
        __syncthreads();
        hist[t] += v;
        __syncthreads();
    }
    sofs[t] = hist[t] - mycnt;        // exclusive local offset
    lcur[t] = hist[t] - mycnt;
    if (mycnt > 0) hbase[t] = atomicAdd(&bcursor[t], mycnt);
    __syncthreads();

    // place payloads into LDS, bucket-major
#pragma unroll
    for (int i = 0; i < 4; ++i) {
        if (bk[i] >= 0) {
            int ls = atomicAdd(&lcur[bk[i]], 1);
            buf[ls] = pl[i];
        }
    }
    __syncthreads();

    // write runs: consecutive LDS slots in a bucket -> consecutive global pos
    int tot = n_edges - base; if (tot > 1024) tot = 1024;
    for (int s = t; s < tot; s += 256) {
        int4 p = buf[s];
        int b = p.w >> BSH;
        tmp[hbase[b] + (s - sofs[b])] = p;
    }
}

// ---------------- scatter pass 2: WG owns one bucket region ----------------
__global__ __launch_bounds__(256) void k_scat2(
        const int4* __restrict__ tmp, const int* __restrict__ off_,
        int* __restrict__ cursor, int4* __restrict__ psort, int n_nodes) {
    int b = blockIdx.x;
    int s0 = off_[b << BSH];
    int hi = (b + 1) << BSH; if (hi > n_nodes) hi = n_nodes;
    int s1 = off_[hi];
    int s = s0 + threadIdx.x;
    for (; s + 768 < s1; s += 1024) {   // 4 atomic chains in flight
        int4 p0 = tmp[s], p1 = tmp[s + 256], p2 = tmp[s + 512], p3 = tmp[s + 768];
        int q0 = atomicAdd(&cursor[p0.w], 1);
        int q1 = atomicAdd(&cursor[p1.w], 1);
        int q2 = atomicAdd(&cursor[p2.w], 1);
        int q3 = atomicAdd(&cursor[p3.w], 1);
        psort[q0] = p0; psort[q1] = p1; psort[q2] = p2; psort[q3] = p3;
    }
    for (; s < s1; s += 256) {
        int4 p = tmp[s];
        psort[atomicAdd(&cursor[p.w], 1)] = p;
    }
}

// ---------------- fallback one-pass scatter (R8 path) ----------------------
__global__ void k_scatter(const int* __restrict__ src, const int* __restrict__ dst,
                          const float* __restrict__ dist, int* __restrict__ cursor,
                          int4* __restrict__ psort, int n_edges) {
    int e = blockIdx.x * blockDim.x + threadIdx.x;
    if (e >= n_edges) return;
    int t = dst[e];
    int pos = atomicAdd(&cursor[t], 1);
    float d = dist[e];
    float A = __expf(-1.125f * d * d);
    float B = __expf(1.5f * d);
    psort[pos] = make_int4(src[e] << 6, __float_as_int(A), __float_as_int(B), 0);
}

// ---------------- gather, feature-half pass ---------------------------------
// lanes 0-31: even edges; lanes 32-63: odd edges; feature = f0 + (lane&31).
// Per pass only 64B of each 128B h row is touched -> 3.2MB working set.
__global__ __launch_bounds__(256, 8) void k_gatherh(
        const int4* __restrict__ ps, const int* __restrict__ off,
        const __half* __restrict__ h,
        const float* __restrict__ We, const float* __restrict__ be,
        float* __restrict__ agg, int n_nodes, int f0) {
    int lane = threadIdx.x & 63;
    int half = lane >> 5;                 // 0: even edges, 1: odd edges
    int fl = (lane & 31) + f0;            // feature index
    int gw = __builtin_amdgcn_readfirstlane((blockIdx.x * blockDim.x + threadIdx.x) >> 6);
    int nw = (gridDim.x * blockDim.x) >> 6;

    const float C[10] = {RBF_C0, RBF_C1, RBF_C2, RBF_C3, RBF_C4,
                         RBF_C5, RBF_C6, RBF_C7, RBF_C8, RBF_C9};
    float wp[10];
#pragma unroll
    for (int r = 0; r < 10; ++r) wp[r] = We[r * 64 + fl] * C[r];
    float bj = be[fl];

    for (int n = gw; n < n_nodes; n += nw) {
        int k0 = off[n], k1 = off[n + 1];
        float acc = 0.0f;
        int k = k0;
        for (; k + 16 <= k1; k += 16) {   // 8 edge-pairs in flight
            int4 p0 = ps[k + 0  + half], p1 = ps[k + 2  + half];
            int4 p2 = ps[k + 4  + half], p3 = ps[k + 6  + half];
            int4 p4 = ps[k + 8  + half], p5 = ps[k + 10 + half];
            int4 p6 = ps[k + 12 + half], p7 = ps[k + 14 + half];
            float g0 = __half2float(h[p0.x + fl]);
            float g1 = __half2float(h[p1.x + fl]);
            float g2 = __half2float(h[p2.x + fl]);
            float g3 = __half2float(h[p3.x + fl]);
            float g4 = __half2float(h[p4.x + fl]);
            float g5 = __half2float(h[p5.x + fl]);
            float g6 = __half2float(h[p6.x + fl]);
            float g7 = __half2float(h[p7.x + fl]);
            acc = fmaf(g0, filt_ab(wp, bj, __int_as_float(p0.y), __int_as_float(p0.z)), acc);
            acc = fmaf(g1, filt_ab(wp, bj, __int_as_float(p1.y), __int_as_float(p1.z)), acc);
            acc = fmaf(g2, filt_ab(wp, bj, __int_as_float(p2.y), __int_as_float(p2.z)), acc);
            acc = fmaf(g3, filt_ab(wp, bj, __int_as_float(p3.y), __int_as_float(p3.z)), acc);
            acc = fmaf(g4, filt_ab(wp, bj, __int_as_float(p4.y), __int_as_float(p4.z)), acc);
            acc = fmaf(g5, filt_ab(wp, bj, __int_as_float(p5.y), __int_as_float(p5.z)), acc);
            acc = fmaf(g6, filt_ab(wp, bj, __int_as_float(p6.y), __int_as_float(p6.z)), acc);
            acc = fmaf(g7, filt_ab(wp, bj, __int_as_float(p7.y), __int_as_float(p7.z)), acc);
        }
        for (; k + 2 <= k1; k += 2) {
            int4 p = ps[k + half];
            float g = __half2float(h[p.x + fl]);
            acc = fmaf(g, filt_ab(wp, bj, __int_as_float(p.y), __int_as_float(p.z)), acc);
        }
        if (k < k1 && half == 0) {        // odd tail edge -> half 0
            int4 p = ps[k];
            float g = __half2float(h[p.x + fl]);
            acc = fmaf(g, filt_ab(wp, bj, __int_as_float(p.y), __int_as_float(p.z)), acc);
        }
        float tot = acc + __shfl_xor(acc, 32);
        if (half == 0) agg[n * 64 + fl] = tot;
    }
}

// ---------------- epilogue: 64-node tile, 512 threads (8 waves x 8 feats) --
// x = softplus(x + agg@W2 + b2); if do_next: hout = half(x@W1n + b1n)
__global__ __launch_bounds__(512) void k_epi(
        const float* __restrict__ agg, float* __restrict__ x,
        const float* __restrict__ W2, const float* __restrict__ b2,
        const float* __restrict__ W1n, const float* __restrict__ b1n,
        __half* __restrict__ hout, int n_nodes, int do_next) {
    __shared__ float B1[64 * 65];        // [node r][feat c], stride 65 (2-way free)
    const int t = threadIdx.x;
    const int lane = t & 63;
    const int wid = __builtin_amdgcn_readfirstlane(t >> 6);   // 0..7
    const int base = blockIdx.x << 6;
    const int nv = min(64, n_nodes - base);

    // ---- stage agg tile (coalesced float4 loads, b32 LDS writes) ----
#pragma unroll
    for (int i = 0; i < 2; ++i) {
        int f = ((wid * 2 + i) << 8) + (lane << 2);   // float idx 0..4095
        int r = f >> 6, c = f & 63;
        int rs = min(r, nv - 1);
        const float4 v = *(const float4*)(agg + (((size_t)(base + rs)) << 6) + c);
        B1[r * 65 + c + 0] = v.x; B1[r * 65 + c + 1] = v.y;
        B1[r * 65 + c + 2] = v.z; B1[r * 65 + c + 3] = v.w;
    }
    __syncthreads();

    // ---- phase1: o[jj] = sum_k agg[lane][k] * W2[k][wid*8+jj] ----
    float o[8];
#pragma unroll
    for (int jj = 0; jj < 8; ++jj) o[jj] = 0.0f;
#pragma unroll 4
    for (int k = 0; k < 64; ++k) {
        float a = B1[lane * 65 + k];
        const float4* w4 = (const float4*)(W2 + (k << 6) + (wid << 3));
        float4 wa = w4[0], wb = w4[1];
        o[0] = fmaf(a, wa.x, o[0]); o[1] = fmaf(a, wa.y, o[1]);
        o[2] = fmaf(a, wa.z, o[2]); o[3] = fmaf(a, wa.w, o[3]);
        o[4] = fmaf(a, wb.x, o[4]); o[5] = fmaf(a, wb.y, o[5]);
        o[6] = fmaf(a, wb.z, o[6]); o[7] = fmaf(a, wb.w, o[7]);
    }
    __syncthreads();

    // ---- restage x tile into the same buffer ----
#pragma unroll
    for (int i = 0; i < 2; ++i) {
        int f = ((wid * 2 + i) << 8) + (lane << 2);
        int r = f >> 6, c = f & 63;
        int rs = min(r, nv - 1);
        const float4 v = *(const float4*)(x + (((size_t)(base + rs)) << 6) + c);
        B1[r * 65 + c + 0] = v.x; B1[r * 65 + c + 1] = v.y;
        B1[r * 65 + c + 2] = v.z; B1[r * 65 + c + 3] = v.w;
    }
    __syncthreads();

    // ---- phase2: xn = softplus(x + o + b2), written back in-place ----
#pragma unroll
    for (int jj = 0; jj < 8; ++jj) {
        int j = (wid << 3) + jj;
        float xv = B1[lane * 65 + j];
        float xn = softplusf(xv + o[jj] + b2[j]);
        B1[lane * 65 + j] = xn;
    }
    __syncthreads();

    // ---- x rows out (coalesced, transposed through LDS) ----
#pragma unroll
    for (int rr = 0; rr < 8; ++rr) {
        int r = (wid << 3) + rr;
        if (r < nv) x[(((size_t)(base + r)) << 6) + lane] = B1[r * 65 + lane];
    }

    if (do_next) {
        // ---- phase3: o2[jj] = b1n[j] + sum_k xn[lane][k] * W1n[k][j] ----
        float o2[8];
#pragma unroll
        for (int jj = 0; jj < 8; ++jj) o2[jj] = b1n[(wid << 3) + jj];
#pragma unroll 4
        for (int k = 0; k < 64; ++k) {
            float xk = B1[lane * 65 + k];
            const float4* w4 = (const float4*)(W1n + (k << 6) + (wid << 3));
            float4 wa = w4[0], wb = w4[1];
            o2[0] = fmaf(xk, wa.x, o2[0]); o2[1] = fmaf(xk, wa.y, o2[1]);
            o2[2] = fmaf(xk, wa.z, o2[2]); o2[3] = fmaf(xk, wa.w, o2[3]);
            o2[4] = fmaf(xk, wb.x, o2[4]); o2[5] = fmaf(xk, wb.y, o2[5]);
            o2[6] = fmaf(xk, wb.z, o2[6]); o2[7] = fmaf(xk, wb.w, o2[7]);
        }
        __syncthreads();   // all reads of xn done -> safe to overwrite
#pragma unroll
        for (int jj = 0; jj < 8; ++jj)
            B1[lane * 65 + (wid << 3) + jj] = o2[jj];
        __syncthreads();
#pragma unroll
        for (int rr = 0; rr < 8; ++rr) {
            int r = (wid << 3) + rr;
            if (r < nv)
                hout[(((size_t)(base + r)) << 6) + lane] = __float2half(B1[r * 65 + lane]);
        }
    }
}

// ---------------- fallback: R8 fused conv (known-good path) ----------------
__global__ __launch_bounds__(256, 6) void k_conv(
        const int4* __restrict__ ps, const int* __restrict__ off,
        const __half* __restrict__ h,
        const float* __restrict__ We, const float* __restrict__ be,
        const float* __restrict__ W2, const float* __restrict__ b2,
        const float* __restrict__ W1n, const float* __restrict__ b1n,
        float* __restrict__ x, __half* __restrict__ hout,
        int n_nodes, int do_next) {
    int lane = threadIdx.x & 63;
    int gw = __builtin_amdgcn_readfirstlane((blockIdx.x * blockDim.x + threadIdx.x) >> 6);
    int nw = (gridDim.x * blockDim.x) >> 6;

    const float C[10] = {RBF_C0, RBF_C1, RBF_C2, RBF_C3, RBF_C4,
                         RBF_C5, RBF_C6, RBF_C7, RBF_C8, RBF_C9};
    float wp[10];
#pragma unroll
    for (int r = 0; r < 10; ++r) wp[r] = We[r * 64 + lane] * C[r];
    float bj  = be[lane];
    float b2j = b2[lane];
    float b1j = do_next ? b1n[lane] : 0.0f;

    for (int n = gw; n < n_nodes; n += nw) {
        int k0 = off[n], k1 = off[n + 1];
        float acc = 0.0f;
        int k = k0;
        for (; k + 8 <= k1; k += 8) {
            int4 p0 = ps[k + 0], p1 = ps[k + 1], p2 = ps[k + 2], p3 = ps[k + 3];
            int4 p4 = ps[k + 4], p5 = ps[k + 5], p6 = ps[k + 6], p7 = ps[k + 7];
            float g0 = __half2float(h[p0.x + lane]);
            float g1 = __half2float(h[p1.x + lane]);
            float g2 = __half2float(h[p2.x + lane]);
            float g3 = __half2float(h[p3.x + lane]);
            float g4 = __half2float(h[p4.x + lane]);
            float g5 = __half2float(h[p5.x + lane]);
            float g6 = __half2float(h[p6.x + lane]);
            float g7 = __half2float(h[p7.x + lane]);
            acc = fmaf(g0, filt_ab(wp, bj, __int_as_float(p0.y), __int_as_float(p0.z)), acc);
            acc = fmaf(g1, filt_ab(wp, bj, __int_as_float(p1.y), __int_as_float(p1.z)), acc);
            acc = fmaf(g2, filt_ab(wp, bj, __int_as_float(p2.y), __int_as_float(p2.z)), acc);
            acc = fmaf(g3, filt_ab(wp, bj, __int_as_float(p3.y), __int_as_float(p3.z)), acc);
            acc = fmaf(g4, filt_ab(wp, bj, __int_as_float(p4.y), __int_as_float(p4.z)), acc);
            acc = fmaf(g5, filt_ab(wp, bj, __int_as_float(p5.y), __int_as_float(p5.z)), acc);
            acc = fmaf(g6, filt_ab(wp, bj, __int_as_float(p6.y), __int_as_float(p6.z)), acc);
            acc = fmaf(g7, filt_ab(wp, bj, __int_as_float(p7.y), __int_as_float(p7.z)), acc);
        }
        for (; k + 4 <= k1; k += 4) {
            int4 p0 = ps[k + 0], p1 = ps[k + 1], p2 = ps[k + 2], p3 = ps[k + 3];
            float g0 = __half2float(h[p0.x + lane]);
            float g1 = __half2float(h[p1.x + lane]);
            float g2 = __half2float(h[p2.x + lane]);
            float g3 = __half2float(h[p3.x + lane]);
            acc = fmaf(g0, filt_ab(wp, bj, __int_as_float(p0.y), __int_as_float(p0.z)), acc);
            acc = fmaf(g1, filt_ab(wp, bj, __int_as_float(p1.y), __int_as_float(p1.z)), acc);
            acc = fmaf(g2, filt_ab(wp, bj, __int_as_float(p2.y), __int_as_float(p2.z)), acc);
            acc = fmaf(g3, filt_ab(wp, bj, __int_as_float(p3.y), __int_as_float(p3.z)), acc);
        }
        for (; k < k1; ++k) {
            int4 p = ps[k];
            float g = __half2float(h[p.x + lane]);
            acc = fmaf(g, filt_ab(wp, bj, __int_as_float(p.y), __int_as_float(p.z)), acc);
        }
        float o0 = b2j + x[n * 64 + lane];
        float o1 = 0.f, o2 = 0.f, o3 = 0.f;
#pragma unroll 4
        for (int kk = 0; kk < 16; ++kk) {
            o0 = fmaf(__shfl(acc, kk),      W2[(kk)      * 64 + lane], o0);
            o1 = fmaf(__shfl(acc, kk + 16), W2[(kk + 16) * 64 + lane], o1);
            o2 = fmaf(__shfl(acc, kk + 32), W2[(kk + 32) * 64 + lane], o2);
            o3 = fmaf(__shfl(acc, kk + 48), W2[(kk + 48) * 64 + lane], o3);
        }
        float xn = softplusf((o0 + o1) + (o2 + o3));
        x[n * 64 + lane] = xn;
        if (do_next) {
            float q0 = b1j, q1 = 0.f, q2 = 0.f, q3 = 0.f;
#pragma unroll 4
            for (int kk = 0; kk < 16; ++kk) {
                q0 = fmaf(__shfl(xn, kk),      W1n[(kk)      * 64 + lane], q0);
                q1 = fmaf(__shfl(xn, kk + 16), W1n[(kk + 16) * 64 + lane], q1);
                q2 = fmaf(__shfl(xn, kk + 32), W1n[(kk + 32) * 64 + lane], q2);
                q3 = fmaf(__shfl(xn, kk + 48), W1n[(kk + 48) * 64 + lane], q3);
            }
            hout[n * 64 + lane] = __float2half((q0 + q1) + (q2 + q3));
        }
    }
}

// ---------------- fused pool + head: one block per graph ----------------
__global__ void k_poolhead(const float* __restrict__ x, const int* __restrict__ gstart,
                           const float* __restrict__ Ws, const float* __restrict__ bs,
                           const float* __restrict__ Wbg1, const float* __restrict__ bbg1,
                           const float* __restrict__ Wbg2, const float* __restrict__ bbg2,
                           const float* __restrict__ Weh1, const float* __restrict__ beh1,
                           const float* __restrict__ Weh2, const float* __restrict__ beh2,
                           float* __restrict__ out, int n_graphs) {
    __shared__ float red[256];
    __shared__ float c[64];
    __shared__ float h1[128];
    int g = blockIdx.x;
    int t = threadIdx.x, j = t & 63, part = t >> 6;
    int s0 = gstart[g], s1 = gstart[g + 1];
    float acc = 0.0f;
    for (int n = s0 + part; n < s1; n += 4) acc += x[n * 64 + j];
    red[t] = acc;
    __syncthreads();
    if (part == 0)
        c[j] = (red[j] + red[64 + j] + red[128 + j] + red[192 + j]) /
               fmaxf((float)(s1 - s0), 1.0f);
    __syncthreads();
    if (t < 128) {
        float av = bs[t];
#pragma unroll 8
        for (int k = 0; k < 64; ++k) av = fmaf(c[k], Ws[k * 128 + t], av);
        h1[t] = fmaxf(av, 0.0f);
    }
    __syncthreads();
    if (t < 128) {
        const float* W1p = (t < 64) ? Wbg1 : Weh1;
        const float* b1p = (t < 64) ? bbg1 : beh1;
        const float* W2p = (t < 64) ? Wbg2 : Weh2;
        float b2v = (t < 64) ? bbg2[0] : beh2[0];
        int ln = t & 63;
        float a2 = b1p[ln];
#pragma unroll 8
        for (int k = 0; k < 128; ++k) a2 = fmaf(h1[k], W1p[k * 64 + ln], a2);
        a2 = fmaxf(a2, 0.0f);
        float pr = a2 * W2p[ln];
#pragma unroll
        for (int off = 32; off > 0; off >>= 1) pr += __shfl_down(pr, off);
        if (ln == 0) out[(t < 64 ? 0 : n_graphs) + g] = pr + b2v;
    }
}

extern "C" void kernel_launch(void* const* d_in, const int* in_sizes, int n_in,
                              void* d_out, int out_size, void* d_ws, size_t ws_size,
                              hipStream_t stream) {
    const int*   x_ids = (const int*)d_in[0];
    const int*   eidx  = (const int*)d_in[1];
    const float* eattr = (const float*)d_in[2];
    const int*   batch = (const int*)d_in[3];
    const float* emb   = (const float*)d_in[4];
    const float* W1    = (const float*)d_in[5];
    const float* b1    = (const float*)d_in[6];
    const float* We    = (const float*)d_in[7];
    const float* be    = (const float*)d_in[8];
    const float* W2    = (const float*)d_in[9];
    const float* b2    = (const float*)d_in[10];
    const float* Ws_   = (const float*)d_in[11];
    const float* bs_   = (const float*)d_in[12];
    const float* Wbg1  = (const float*)d_in[13];
    const float* bbg1  = (const float*)d_in[14];
    const float* Wbg2  = (const float*)d_in[15];
    const float* bbg2  = (const float*)d_in[16];
    const float* Weh1  = (const float*)d_in[17];
    const float* beh1  = (const float*)d_in[18];
    const float* Weh2  = (const float*)d_in[19];
    const float* beh2  = (const float*)d_in[20];

    int n_nodes  = in_sizes[0];
    int n_edges  = in_sizes[2];
    int n_graphs = out_size / 2;
    const int* src = eidx;
    const int* dst = eidx + n_edges;
    int nbuck = (n_nodes + (1 << BSH) - 1) >> BSH;
    int nbc = (nbuck < 256 ? 256 : nbuck) + 4;   // bcursor alloc (>=256 for scat1)

    // base footprint
    size_t base_bytes =
        (size_t)n_nodes * 64 * sizeof(float)      // x
      + (size_t)n_nodes * 64 * sizeof(__half) * 2 // hA, hB
      + (size_t)n_edges * sizeof(int4)            // psort
      + (size_t)n_nodes * sizeof(int) * 2         // deg, cursor
      + (size_t)(n_nodes + 1) * sizeof(int)       // off
      + 256 * sizeof(int)                         // bsum
      + (size_t)(n_graphs + 1) * sizeof(int)      // gstart
      + (size_t)nbc * sizeof(int);                // bcursor
    size_t agg_bytes = (size_t)n_nodes * 64 * sizeof(float);
    size_t tmp_bytes = (size_t)n_edges * sizeof(int4);
    size_t aggtmp_bytes = agg_bytes > tmp_bytes ? agg_bytes : tmp_bytes;
    int use_split = (ws_size >= base_bytes + aggtmp_bytes + 1024) ? 1 : 0;

    char* p = (char*)d_ws;
    float* x     = (float*)p;   p += (size_t)n_nodes * 64 * sizeof(float);
    __half* hA   = (__half*)p;  p += (size_t)n_nodes * 64 * sizeof(__half);
    __half* hB   = (__half*)p;  p += (size_t)n_nodes * 64 * sizeof(__half);
    int4* psort  = (int4*)p;    p += (size_t)n_edges * sizeof(int4);
    int* deg     = (int*)p;     p += (size_t)n_nodes * sizeof(int);
    int* off_    = (int*)p;     p += (size_t)(n_nodes + 1) * sizeof(int);
    int* cursor  = (int*)p;     p += (size_t)n_nodes * sizeof(int);
    int* bsum    = (int*)p;     p += 256 * sizeof(int);
    int* gstart  = (int*)p;     p += (size_t)(n_graphs + 1) * sizeof(int);
    int* bcursor = (int*)p;     p += (size_t)nbc * sizeof(int);
    float* agg   = (float*)p;   // aliases tmp; only touched if use_split
    int4* tmp    = (int4*)p;
    float* out   = (float*)d_out;

    int nchunks = (n_nodes + 255) / 256;
    int nbE = (n_edges + 255) / 256;
    int nbN = (n_nodes + 255) / 256;
    int ntile = (n_nodes + 63) / 64;
    int nbS1 = (n_edges + 1023) / 1024;

    hipMemsetAsync(deg, 0, (size_t)n_nodes * sizeof(int), stream);
    k_pre<<<nbE, 256, 0, stream>>>(dst, deg, batch, gstart, x_ids, emb, W1, b1,
                                   x, hA, n_edges, n_nodes, n_graphs);
    k_scana<<<nchunks, 256, 0, stream>>>(deg, off_, bsum, n_nodes);
    k_scanb<<<1, 256, 0, stream>>>(bsum, nchunks);
    k_scanc<<<nbN, 256, 0, stream>>>(deg, bsum, off_, cursor, bcursor, n_nodes);

    if (use_split) {
        k_scat1<<<nbS1, 256, 0, stream>>>(src, dst, eattr, bcursor, tmp, n_edges);
        k_scat2<<<nbuck, 256, 0, stream>>>(tmp, off_, cursor, psort, n_nodes);
        // conv 0
        k_gatherh<<<4096, 256, 0, stream>>>(psort, off_, hA, We, be, agg, n_nodes, 0);
        k_gatherh<<<4096, 256, 0, stream>>>(psort, off_, hA, We, be, agg, n_nodes, 32);
        k_epi<<<ntile, 512, 0, stream>>>(agg, x, W2, b2,
                                         W1 + 4096, b1 + 64, hB, n_nodes, 1);
        // conv 1
        k_gatherh<<<4096, 256, 0, stream>>>(psort, off_, hB, We + 640, be + 64, agg, n_nodes, 0);
        k_gatherh<<<4096, 256, 0, stream>>>(psort, off_, hB, We + 640, be + 64, agg, n_nodes, 32);
        k_epi<<<ntile, 512, 0, stream>>>(agg, x, W2 + 4096, b2 + 64,
                                         W1 + 8192, b1 + 128, hA, n_nodes, 1);
        // conv 2
        k_gatherh<<<4096, 256, 0, stream>>>(psort, off_, hA, We + 1280, be + 128, agg, n_nodes, 0);
        k_gatherh<<<4096, 256, 0, stream>>>(psort, off_, hA, We + 1280, be + 128, agg, n_nodes, 32);
        k_epi<<<ntile, 512, 0, stream>>>(agg, x, W2 + 8192, b2 + 128,
                                         nullptr, nullptr, nullptr, n_nodes, 0);
    } else {
        k_scatter<<<nbE, 256, 0, stream>>>(src, dst, eattr, cursor, psort, n_edges);
        k_conv<<<4096, 256, 0, stream>>>(psort, off_, hA, We, be, W2, b2,
                                         W1 + 4096, b1 + 64, x, hB, n_nodes, 1);
        k_conv<<<4096, 256, 0, stream>>>(psort, off_, hB, We + 640, be + 64,
                                         W2 + 4096, b2 + 64,
                                         W1 + 8192, b1 + 128, x, hA, n_nodes, 1);
        k_conv<<<4096, 256, 0, stream>>>(psort, off_, hA, We + 1280, be + 128,
                                         W2 + 8192, b2 + 128,
                                         nullptr, nullptr, x, nullptr, n_nodes, 0);
    }

    k_poolhead<<<n_graphs, 256, 0, stream>>>(x, gstart, Ws_, bs_, Wbg1, bbg1, Wbg2, bbg2,
                                             Weh1, beh1, Weh2, beh2, out, n_graphs);
}

// Round 17
// 378.668 us; speedup vs baseline: 1.2532x; 1.2532x over previous
//
#include <hip/hip_runtime.h>
#include <hip/hip_fp16.h>
#include <cstddef>

// ---------------------------------------------------------------------------
// CrystalGNN (SchNet-style). R25 = R20/R22 verbatim — FINAL (session best,
// reproduced 3x: 380.1 / 380.9 / 379.1 us; baseline was 435.5).
//   Wins kept: split conv (gather 4096-blk + tile epi), ownership 2-pass
//   scatter, 512-thread epi (8 waves x 8 feats), 16-deep gather.
//   Falsified this session (all reverted): shuffle-staged payloads (+10),
//   gather+epi fusion (+34, occupancy), W-in-VGPR epi (spill/reload),
//   single-block scan (+109, serial), int2 payloads (+17, exp on
//   transcendental pipe), feature-half gather (+95, working-set theory
//   wrong: concurrent blocks span all of h; halves waste fetched lines).
//   Gather x3 ~ 120us is the structural floor: compulsory random 128B
//   h-row L2 misses across 8 non-coherent XCD L2s (~33MB/layer).
//   Layout: memset deg / k_pre / scana/b/c / k_scat1 / k_scat2 /
//   3x{k_gather, k_epi} / k_poolhead.
//   fallback (ws too small): R8 fused k_conv + one-pass scatter.
// ---------------------------------------------------------------------------

#define BSH 8   // 256 nodes per scatter bucket

// C_r = exp(-0.5 r^2), r = 0..9
#define RBF_C0 1.0f
#define RBF_C1 0.60653065971f
#define RBF_C2 0.13533528324f
#define RBF_C3 0.011108996538f
#define RBF_C4 3.3546262790e-4f
#define RBF_C5 3.7266531720e-6f
#define RBF_C6 1.5229979745e-8f
#define RBF_C7 2.2897348457e-11f
#define RBF_C8 1.2664165549e-14f
#define RBF_C9 2.5767043600e-18f

__device__ __forceinline__ float softplusf(float v) {
    return fmaxf(v, 0.0f) + log1pf(__expf(-fabsf(v)));
}

__device__ __forceinline__ float row_gemv(const float4* __restrict__ xr,
                                          const float w[64], float bj) {
    float a0 = bj, a1 = 0.f, a2 = 0.f, a3 = 0.f;
#pragma unroll
    for (int q = 0; q < 4; ++q) {
        float4 v0 = xr[4 * q + 0], v1 = xr[4 * q + 1];
        float4 v2 = xr[4 * q + 2], v3 = xr[4 * q + 3];
        a0 = fmaf(v0.x, w[16 * q + 0], a0);  a0 = fmaf(v0.y, w[16 * q + 1], a0);
        a0 = fmaf(v0.z, w[16 * q + 2], a0);  a0 = fmaf(v0.w, w[16 * q + 3], a0);
        a1 = fmaf(v1.x, w[16 * q + 4], a1);  a1 = fmaf(v1.y, w[16 * q + 5], a1);
        a1 = fmaf(v1.z, w[16 * q + 6], a1);  a1 = fmaf(v1.w, w[16 * q + 7], a1);
        a2 = fmaf(v2.x, w[16 * q + 8], a2);  a2 = fmaf(v2.y, w[16 * q + 9], a2);
        a2 = fmaf(v2.z, w[16 * q + 10], a2); a2 = fmaf(v2.w, w[16 * q + 11], a2);
        a3 = fmaf(v3.x, w[16 * q + 12], a3); a3 = fmaf(v3.y, w[16 * q + 13], a3);
        a3 = fmaf(v3.z, w[16 * q + 14], a3); a3 = fmaf(v3.w, w[16 * q + 15], a3);
    }
    return (a0 + a1) + (a2 + a3);
}

__device__ __forceinline__ float filt_ab(const float wp[10], float bj, float A, float B) {
    float P = wp[9];
    P = fmaf(B, P, wp[8]); P = fmaf(B, P, wp[7]); P = fmaf(B, P, wp[6]);
    P = fmaf(B, P, wp[5]); P = fmaf(B, P, wp[4]); P = fmaf(B, P, wp[3]);
    P = fmaf(B, P, wp[2]); P = fmaf(B, P, wp[1]); P = fmaf(B, P, wp[0]);
    return fmaf(A, P, bj);
}

// ---------------- hist + gstart + embed + gemm0 (independent passes) -------
__global__ void k_pre(const int* __restrict__ dst, int* __restrict__ deg,
                      const int* __restrict__ batch, int* __restrict__ gstart,
                      const int* __restrict__ ids, const float* __restrict__ emb,
                      const float* __restrict__ W1, const float* __restrict__ b1,
                      float* __restrict__ x, __half* __restrict__ hA,
                      int n_edges, int n_nodes, int n_graphs) {
    int tid = blockIdx.x * blockDim.x + threadIdx.x;
    int nth = gridDim.x * blockDim.x;
    for (int e = tid; e < n_edges; e += nth) atomicAdd(&deg[dst[e]], 1);
    for (int n = tid; n < n_nodes; n += nth) {
        int b = batch[n];
        int prev = (n == 0) ? -1 : batch[n - 1];
        for (int g = prev + 1; g <= b; ++g) gstart[g] = n;
        if (n == n_nodes - 1)
            for (int g = b + 1; g <= n_graphs; ++g) gstart[g] = n_nodes;
    }
    // gemm0: x = emb[ids], hA = x @ W1[0] + b1[0]
    int lane = threadIdx.x & 63;
    int gw = __builtin_amdgcn_readfirstlane(tid >> 6);
    int nw = nth >> 6;
    float w[64];
#pragma unroll
    for (int k = 0; k < 64; ++k) w[k] = W1[k * 64 + lane];
    float bj = b1[lane];
    for (int n = gw; n < n_nodes; n += nw) {
        int id = __builtin_amdgcn_readfirstlane(ids[n]);
        const float4* xr = (const float4*)(emb + id * 64);
        float v = row_gemv(xr, w, bj);
        x[n * 64 + lane] = emb[id * 64 + lane];
        hA[n * 64 + lane] = __float2half(v);
    }
}

// ---------------- scan ----------------
__global__ void k_scana(const int* __restrict__ deg, int* __restrict__ off_,
                        int* __restrict__ bsum, int n) {
    __shared__ int s[256];
    int i = blockIdx.x * 256 + threadIdx.x;
    int v = (i < n) ? deg[i] : 0;
    s[threadIdx.x] = v;
    __syncthreads();
    for (int off = 1; off < 256; off <<= 1) {
        int t = (threadIdx.x >= off) ? s[threadIdx.x - off] : 0;
        __syncthreads();
        s[threadIdx.x] += t;
        __syncthreads();
    }
    if (i < n) off_[i + 1] = s[threadIdx.x];
    if (threadIdx.x == 255) bsum[blockIdx.x] = s[255];
}

__global__ void k_scanb(int* __restrict__ bsum, int nb) {
    __shared__ int s[256];
    int v = ((int)threadIdx.x < nb) ? bsum[threadIdx.x] : 0;
    s[threadIdx.x] = v;
    __syncthreads();
    for (int off = 1; off < 256; off <<= 1) {
        int t = (threadIdx.x >= off) ? s[threadIdx.x - off] : 0;
        __syncthreads();
        s[threadIdx.x] += t;
        __syncthreads();
    }
    if ((int)threadIdx.x < nb) bsum[threadIdx.x] = s[threadIdx.x] - v;  // exclusive
}

__global__ void k_scanc(const int* __restrict__ deg, const int* __restrict__ bsum,
                        int* __restrict__ off_, int* __restrict__ cursor,
                        int* __restrict__ bcursor, int n) {
    int i = blockIdx.x * blockDim.x + threadIdx.x;
    if (i < n) {
        int incl = off_[i + 1] + bsum[i >> 8];
        off_[i + 1] = incl;
        cursor[i] = incl - deg[i];
        // bucket start: bcursor[b] = off_[b<<BSH]
        if (((i + 1) & ((1 << BSH) - 1)) == 0)
            bcursor[(i + 1) >> BSH] = incl;
    }
    if (i == 0) { off_[0] = 0; bcursor[0] = 0; }
}

// ---------------- scatter pass 1: LDS counting-sort into bucket runs -------
__global__ __launch_bounds__(256) void k_scat1(
        const int* __restrict__ src, const int* __restrict__ dst,
        const float* __restrict__ dist, int* __restrict__ bcursor,
        int4* __restrict__ tmp, int n_edges) {
    __shared__ int hist[256], sofs[256], hbase[256], lcur[256];
    __shared__ int4 buf[1024];
    const int t = threadIdx.x;
    const int base = blockIdx.x << 10;

    hist[t] = 0;
    __syncthreads();

    int bk[4]; int4 pl[4];
#pragma unroll
    for (int i = 0; i < 4; ++i) {
        int e = base + (i << 8) + t;
        if (e < n_edges) {
            int d_ = dst[e];
            float dd = dist[e];
            float A = __expf(-1.125f * dd * dd);
            float B = __expf(1.5f * dd);
            pl[i] = make_int4(src[e] << 6, __float_as_int(A), __float_as_int(B), d_);
            bk[i] = d_ >> BSH;
            atomicAdd(&hist[bk[i]], 1);
        } else bk[i] = -1;
    }
    __syncthreads();

    int mycnt = hist[t];
    // inclusive Hillis-Steele scan over 256 entries
    for (int off = 1; off < 256; off <<= 1) {
        int v = (t >= off) ? hist[t - off] : 0;
        __syncthreads();
        hist[t] += v;
        __syncthreads();
    }
    sofs[t] = hist[t] - mycnt;        // exclusive local offset
    lcur[t] = hist[t] - mycnt;
    if (mycnt > 0) hbase[t] = atomicAdd(&bcursor[t], mycnt);
    __syncthreads();

    // place payloads into LDS, bucket-major
#pragma unroll
    for (int i = 0; i < 4; ++i) {
        if (bk[i] >= 0) {
            int ls = atomicAdd(&lcur[bk[i]], 1);
            buf[ls] = pl[i];
        }
    }
    __syncthreads();

    // write runs: consecutive LDS slots in a bucket -> consecutive global pos
    int tot = n_edges - base; if (tot > 1024) tot = 1024;
    for (int s = t; s < tot; s += 256) {
        int4 p = buf[s];
        int b = p.w >> BSH;
        tmp[hbase[b] + (s - sofs[b])] = p;
    }
}

// ---------------- scatter pass 2: WG owns one bucket region ----------------
__global__ __launch_bounds__(256) void k_scat2(
        const int4* __restrict__ tmp, const int* __restrict__ off_,
        int* __restrict__ cursor, int4* __restrict__ psort, int n_nodes) {
    int b = blockIdx.x;
    int s0 = off_[b << BSH];
    int hi = (b + 1) << BSH; if (hi > n_nodes) hi = n_nodes;
    int s1 = off_[hi];
    int s = s0 + threadIdx.x;
    for (; s + 768 < s1; s += 1024) {   // 4 atomic chains in flight
        int4 p0 = tmp[s], p1 = tmp[s + 256], p2 = tmp[s + 512], p3 = tmp[s + 768];
        int q0 = atomicAdd(&cursor[p0.w], 1);
        int q1 = atomicAdd(&cursor[p1.w], 1);
        int q2 = atomicAdd(&cursor[p2.w], 1);
        int q3 = atomicAdd(&cursor[p3.w], 1);
        psort[q0] = p0; psort[q1] = p1; psort[q2] = p2; psort[q3] = p3;
    }
    for (; s < s1; s += 256) {
        int4 p = tmp[s];
        psort[atomicAdd(&cursor[p.w], 1)] = p;
    }
}

// ---------------- fallback one-pass scatter (R8 path) ----------------------
__global__ void k_scatter(const int* __restrict__ src, const int* __restrict__ dst,
                          const float* __restrict__ dist, int* __restrict__ cursor,
                          int4* __restrict__ psort, int n_edges) {
    int e = blockIdx.x * blockDim.x + threadIdx.x;
    if (e >= n_edges) return;
    int t = dst[e];
    int pos = atomicAdd(&cursor[t], 1);
    float d = dist[e];
    float A = __expf(-1.125f * d * d);
    float B = __expf(1.5f * d);
    psort[pos] = make_int4(src[e] << 6, __float_as_int(A), __float_as_int(B), 0);
}

// ---------------- gather-only conv: 16-deep pipeline -----------------------
__global__ __launch_bounds__(256, 8) void k_gather(
        const int4* __restrict__ ps, const int* __restrict__ off,
        const __half* __restrict__ h,
        const float* __restrict__ We, const float* __restrict__ be,
        float* __restrict__ agg, int n_nodes) {
    int lane = threadIdx.x & 63;
    int gw = __builtin_amdgcn_readfirstlane((blockIdx.x * blockDim.x + threadIdx.x) >> 6);
    int nw = (gridDim.x * blockDim.x) >> 6;

    const float C[10] = {RBF_C0, RBF_C1, RBF_C2, RBF_C3, RBF_C4,
                         RBF_C5, RBF_C6, RBF_C7, RBF_C8, RBF_C9};
    float wp[10];
#pragma unroll
    for (int r = 0; r < 10; ++r) wp[r] = We[r * 64 + lane] * C[r];
    float bj = be[lane];

    for (int n = gw; n < n_nodes; n += nw) {
        int k0 = off[n], k1 = off[n + 1];
        float acc = 0.0f;
        int k = k0;
        for (; k + 16 <= k1; k += 16) {   // 16 gathers in flight
            int4 p0 = ps[k + 0],  p1 = ps[k + 1],  p2 = ps[k + 2],  p3 = ps[k + 3];
            int4 p4 = ps[k + 4],  p5 = ps[k + 5],  p6 = ps[k + 6],  p7 = ps[k + 7];
            int4 p8 = ps[k + 8],  p9 = ps[k + 9],  pa = ps[k + 10], pb = ps[k + 11];
            int4 pc = ps[k + 12], pd = ps[k + 13], pe = ps[k + 14], pf = ps[k + 15];
            float g0 = __half2float(h[p0.x + lane]);
            float g1 = __half2float(h[p1.x + lane]);
            float g2 = __half2float(h[p2.x + lane]);
            float g3 = __half2float(h[p3.x + lane]);
            float g4 = __half2float(h[p4.x + lane]);
            float g5 = __half2float(h[p5.x + lane]);
            float g6 = __half2float(h[p6.x + lane]);
            float g7 = __half2float(h[p7.x + lane]);
            float g8 = __half2float(h[p8.x + lane]);
            float g9 = __half2float(h[p9.x + lane]);
            float ga = __half2float(h[pa.x + lane]);
            float gb = __half2float(h[pb.x + lane]);
            float gc = __half2float(h[pc.x + lane]);
            float gd = __half2float(h[pd.x + lane]);
            float ge = __half2float(h[pe.x + lane]);
            float gf = __half2float(h[pf.x + lane]);
            acc = fmaf(g0, filt_ab(wp, bj, __int_as_float(p0.y), __int_as_float(p0.z)), acc);
            acc = fmaf(g1, filt_ab(wp, bj, __int_as_float(p1.y), __int_as_float(p1.z)), acc);
            acc = fmaf(g2, filt_ab(wp, bj, __int_as_float(p2.y), __int_as_float(p2.z)), acc);
            acc = fmaf(g3, filt_ab(wp, bj, __int_as_float(p3.y), __int_as_float(p3.z)), acc);
            acc = fmaf(g4, filt_ab(wp, bj, __int_as_float(p4.y), __int_as_float(p4.z)), acc);
            acc = fmaf(g5, filt_ab(wp, bj, __int_as_float(p5.y), __int_as_float(p5.z)), acc);
            acc = fmaf(g6, filt_ab(wp, bj, __int_as_float(p6.y), __int_as_float(p6.z)), acc);
            acc = fmaf(g7, filt_ab(wp, bj, __int_as_float(p7.y), __int_as_float(p7.z)), acc);
            acc = fmaf(g8, filt_ab(wp, bj, __int_as_float(p8.y), __int_as_float(p8.z)), acc);
            acc = fmaf(g9, filt_ab(wp, bj, __int_as_float(p9.y), __int_as_float(p9.z)), acc);
            acc = fmaf(ga, filt_ab(wp, bj, __int_as_float(pa.y), __int_as_float(pa.z)), acc);
            acc = fmaf(gb, filt_ab(wp, bj, __int_as_float(pb.y), __int_as_float(pb.z)), acc);
            acc = fmaf(gc, filt_ab(wp, bj, __int_as_float(pc.y), __int_as_float(pc.z)), acc);
            acc = fmaf(gd, filt_ab(wp, bj, __int_as_float(pd.y), __int_as_float(pd.z)), acc);
            acc = fmaf(ge, filt_ab(wp, bj, __int_as_float(pe.y), __int_as_float(pe.z)), acc);
            acc = fmaf(gf, filt_ab(wp, bj, __int_as_float(pf.y), __int_as_float(pf.z)), acc);
        }
        for (; k + 4 <= k1; k += 4) {
            int4 p0 = ps[k + 0], p1 = ps[k + 1], p2 = ps[k + 2], p3 = ps[k + 3];
            float g0 = __half2float(h[p0.x + lane]);
            float g1 = __half2float(h[p1.x + lane]);
            float g2 = __half2float(h[p2.x + lane]);
            float g3 = __half2float(h[p3.x + lane]);
            acc = fmaf(g0, filt_ab(wp, bj, __int_as_float(p0.y), __int_as_float(p0.z)), acc);
            acc = fmaf(g1, filt_ab(wp, bj, __int_as_float(p1.y), __int_as_float(p1.z)), acc);
            acc = fmaf(g2, filt_ab(wp, bj, __int_as_float(p2.y), __int_as_float(p2.z)), acc);
            acc = fmaf(g3, filt_ab(wp, bj, __int_as_float(p3.y), __int_as_float(p3.z)), acc);
        }
        for (; k < k1; ++k) {
            int4 p = ps[k];
            float g = __half2float(h[p.x + lane]);
            acc = fmaf(g, filt_ab(wp, bj, __int_as_float(p.y), __int_as_float(p.z)), acc);
        }
        agg[n * 64 + lane] = acc;
    }
}

// ---------------- epilogue: 64-node tile, 512 threads (8 waves x 8 feats) --
// x = softplus(x + agg@W2 + b2); if do_next: hout = half(x@W1n + b1n)
__global__ __launch_bounds__(512) void k_epi(
        const float* __restrict__ agg, float* __restrict__ x,
        const float* __restrict__ W2, const float* __restrict__ b2,
        const float* __restrict__ W1n, const float* __restrict__ b1n,
        __half* __restrict__ hout, int n_nodes, int do_next) {
    __shared__ float B1[64 * 65];        // [node r][feat c], stride 65 (2-way free)
    const int t = threadIdx.x;
    const int lane = t & 63;
    const int wid = __builtin_amdgcn_readfirstlane(t >> 6);   // 0..7
    const int base = blockIdx.x << 6;
    const int nv = min(64, n_nodes - base);

    // ---- stage agg tile (coalesced float4 loads, b32 LDS writes) ----
#pragma unroll
    for (int i = 0; i < 2; ++i) {
        int f = ((wid * 2 + i) << 8) + (lane << 2);   // float idx 0..4095
        int r = f >> 6, c = f & 63;
        int rs = min(r, nv - 1);
        const float4 v = *(const float4*)(agg + (((size_t)(base + rs)) << 6) + c);
        B1[r * 65 + c + 0] = v.x; B1[r * 65 + c + 1] = v.y;
        B1[r * 65 + c + 2] = v.z; B1[r * 65 + c + 3] = v.w;
    }
    __syncthreads();

    // ---- phase1: o[jj] = sum_k agg[lane][k] * W2[k][wid*8+jj] ----
    float o[8];
#pragma unroll
    for (int jj = 0; jj < 8; ++jj) o[jj] = 0.0f;
#pragma unroll 4
    for (int k = 0; k < 64; ++k) {
        float a = B1[lane * 65 + k];
        const float4* w4 = (const float4*)(W2 + (k << 6) + (wid << 3));
        float4 wa = w4[0], wb = w4[1];
        o[0] = fmaf(a, wa.x, o[0]); o[1] = fmaf(a, wa.y, o[1]);
        o[2] = fmaf(a, wa.z, o[2]); o[3] = fmaf(a, wa.w, o[3]);
        o[4] = fmaf(a, wb.x, o[4]); o[5] = fmaf(a, wb.y, o[5]);
        o[6] = fmaf(a, wb.z, o[6]); o[7] = fmaf(a, wb.w, o[7]);
    }
    __syncthreads();

    // ---- restage x tile into the same buffer ----
#pragma unroll
    for (int i = 0; i < 2; ++i) {
        int f = ((wid * 2 + i) << 8) + (lane << 2);
        int r = f >> 6, c = f & 63;
        int rs = min(r, nv - 1);
        const float4 v = *(const float4*)(x + (((size_t)(base + rs)) << 6) + c);
        B1[r * 65 + c + 0] = v.x; B1[r * 65 + c + 1] = v.y;
        B1[r * 65 + c + 2] = v.z; B1[r * 65 + c + 3] = v.w;
    }
    __syncthreads();

    // ---- phase2: xn = softplus(x + o + b2), written back in-place ----
#pragma unroll
    for (int jj = 0; jj < 8; ++jj) {
        int j = (wid << 3) + jj;
        float xv = B1[lane * 65 + j];
        float xn = softplusf(xv + o[jj] + b2[j]);
        B1[lane * 65 + j] = xn;
    }
    __syncthreads();

    // ---- x rows out (coalesced, transposed through LDS) ----
#pragma unroll
    for (int rr = 0; rr < 8; ++rr) {
        int r = (wid << 3) + rr;
        if (r < nv) x[(((size_t)(base + r)) << 6) + lane] = B1[r * 65 + lane];
    }

    if (do_next) {
        // ---- phase3: o2[jj] = b1n[j] + sum_k xn[lane][k] * W1n[k][j] ----
        float o2[8];
#pragma unroll
        for (int jj = 0; jj < 8; ++jj) o2[jj] = b1n[(wid << 3) + jj];
#pragma unroll 4
        for (int k = 0; k < 64; ++k) {
            float xk = B1[lane * 65 + k];
            const float4* w4 = (const float4*)(W1n + (k << 6) + (wid << 3));
            float4 wa = w4[0], wb = w4[1];
            o2[0] = fmaf(xk, wa.x, o2[0]); o2[1] = fmaf(xk, wa.y, o2[1]);
            o2[2] = fmaf(xk, wa.z, o2[2]); o2[3] = fmaf(xk, wa.w, o2[3]);
            o2[4] = fmaf(xk, wb.x, o2[4]); o2[5] = fmaf(xk, wb.y, o2[5]);
            o2[6] = fmaf(xk, wb.z, o2[6]); o2[7] = fmaf(xk, wb.w, o2[7]);
        }
        __syncthreads();   // all reads of xn done -> safe to overwrite
#pragma unroll
        for (int jj = 0; jj < 8; ++jj)
            B1[lane * 65 + (wid << 3) + jj] = o2[jj];
        __syncthreads();
#pragma unroll
        for (int rr = 0; rr < 8; ++rr) {
            int r = (wid << 3) + rr;
            if (r < nv)
                hout[(((size_t)(base + r)) << 6) + lane] = __float2half(B1[r * 65 + lane]);
        }
    }
}

// ---------------- fallback: R8 fused conv (known-good path) ----------------
__global__ __launch_bounds__(256, 6) void k_conv(
        const int4* __restrict__ ps, const int* __restrict__ off,
        const __half* __restrict__ h,
        const float* __restrict__ We, const float* __restrict__ be,
        const float* __restrict__ W2, const float* __restrict__ b2,
        const float* __restrict__ W1n, const float* __restrict__ b1n,
        float* __restrict__ x, __half* __restrict__ hout,
        int n_nodes, int do_next) {
    int lane = threadIdx.x & 63;
    int gw = __builtin_amdgcn_readfirstlane((blockIdx.x * blockDim.x + threadIdx.x) >> 6);
    int nw = (gridDim.x * blockDim.x) >> 6;

    const float C[10] = {RBF_C0, RBF_C1, RBF_C2, RBF_C3, RBF_C4,
                         RBF_C5, RBF_C6, RBF_C7, RBF_C8, RBF_C9};
    float wp[10];
#pragma unroll
    for (int r = 0; r < 10; ++r) wp[r] = We[r * 64 + lane] * C[r];
    float bj  = be[lane];
    float b2j = b2[lane];
    float b1j = do_next ? b1n[lane] : 0.0f;

    for (int n = gw; n < n_nodes; n += nw) {
        int k0 = off[n], k1 = off[n + 1];
        float acc = 0.0f;
        int k = k0;
        for (; k + 8 <= k1; k += 8) {
            int4 p0 = ps[k + 0], p1 = ps[k + 1], p2 = ps[k + 2], p3 = ps[k + 3];
            int4 p4 = ps[k + 4], p5 = ps[k + 5], p6 = ps[k + 6], p7 = ps[k + 7];
            float g0 = __half2float(h[p0.x + lane]);
            float g1 = __half2float(h[p1.x + lane]);
            float g2 = __half2float(h[p2.x + lane]);
            float g3 = __half2float(h[p3.x + lane]);
            float g4 = __half2float(h[p4.x + lane]);
            float g5 = __half2float(h[p5.x + lane]);
            float g6 = __half2float(h[p6.x + lane]);
            float g7 = __half2float(h[p7.x + lane]);
            acc = fmaf(g0, filt_ab(wp, bj, __int_as_float(p0.y), __int_as_float(p0.z)), acc);
            acc = fmaf(g1, filt_ab(wp, bj, __int_as_float(p1.y), __int_as_float(p1.z)), acc);
            acc = fmaf(g2, filt_ab(wp, bj, __int_as_float(p2.y), __int_as_float(p2.z)), acc);
            acc = fmaf(g3, filt_ab(wp, bj, __int_as_float(p3.y), __int_as_float(p3.z)), acc);
            acc = fmaf(g4, filt_ab(wp, bj, __int_as_float(p4.y), __int_as_float(p4.z)), acc);
            acc = fmaf(g5, filt_ab(wp, bj, __int_as_float(p5.y), __int_as_float(p5.z)), acc);
            acc = fmaf(g6, filt_ab(wp, bj, __int_as_float(p6.y), __int_as_float(p6.z)), acc);
            acc = fmaf(g7, filt_ab(wp, bj, __int_as_float(p7.y), __int_as_float(p7.z)), acc);
        }
        for (; k + 4 <= k1; k += 4) {
            int4 p0 = ps[k + 0], p1 = ps[k + 1], p2 = ps[k + 2], p3 = ps[k + 3];
            float g0 = __half2float(h[p0.x + lane]);
            float g1 = __half2float(h[p1.x + lane]);
            float g2 = __half2float(h[p2.x + lane]);
            float g3 = __half2float(h[p3.x + lane]);
            acc = fmaf(g0, filt_ab(wp, bj, __int_as_float(p0.y), __int_as_float(p0.z)), acc);
            acc = fmaf(g1, filt_ab(wp, bj, __int_as_float(p1.y), __int_as_float(p1.z)), acc);
            acc = fmaf(g2, filt_ab(wp, bj, __int_as_float(p2.y), __int_as_float(p2.z)), acc);
            acc = fmaf(g3, filt_ab(wp, bj, __int_as_float(p3.y), __int_as_float(p3.z)), acc);
        }
        for (; k < k1; ++k) {
            int4 p = ps[k];
            float g = __half2float(h[p.x + lane]);
            acc = fmaf(g, filt_ab(wp, bj, __int_as_float(p.y), __int_as_float(p.z)), acc);
        }
        float o0 = b2j + x[n * 64 + lane];
        float o1 = 0.f, o2 = 0.f, o3 = 0.f;
#pragma unroll 4
        for (int kk = 0; kk < 16; ++kk) {
            o0 = fmaf(__shfl(acc, kk),      W2[(kk)      * 64 + lane], o0);
            o1 = fmaf(__shfl(acc, kk + 16), W2[(kk + 16) * 64 + lane], o1);
            o2 = fmaf(__shfl(acc, kk + 32), W2[(kk + 32) * 64 + lane], o2);
            o3 = fmaf(__shfl(acc, kk + 48), W2[(kk + 48) * 64 + lane], o3);
        }
        float xn = softplusf((o0 + o1) + (o2 + o3));
        x[n * 64 + lane] = xn;
        if (do_next) {
            float q0 = b1j, q1 = 0.f, q2 = 0.f, q3 = 0.f;
#pragma unroll 4
            for (int kk = 0; kk < 16; ++kk) {
                q0 = fmaf(__shfl(xn, kk),      W1n[(kk)      * 64 + lane], q0);
                q1 = fmaf(__shfl(xn, kk + 16), W1n[(kk + 16) * 64 + lane], q1);
                q2 = fmaf(__shfl(xn, kk + 32), W1n[(kk + 32) * 64 + lane], q2);
                q3 = fmaf(__shfl(xn, kk + 48), W1n[(kk + 48) * 64 + lane], q3);
            }
            hout[n * 64 + lane] = __float2half((q0 + q1) + (q2 + q3));
        }
    }
}

// ---------------- fused pool + head: one block per graph ----------------
__global__ void k_poolhead(const float* __restrict__ x, const int* __restrict__ gstart,
                           const float* __restrict__ Ws, const float* __restrict__ bs,
                           const float* __restrict__ Wbg1, const float* __restrict__ bbg1,
                           const float* __restrict__ Wbg2, const float* __restrict__ bbg2,
                           const float* __restrict__ Weh1, const float* __restrict__ beh1,
                           const float* __restrict__ Weh2, const float* __restrict__ beh2,
                           float* __restrict__ out, int n_graphs) {
    __shared__ float red[256];
    __shared__ float c[64];
    __shared__ float h1[128];
    int g = blockIdx.x;
    int t = threadIdx.x, j = t & 63, part = t >> 6;
    int s0 = gstart[g], s1 = gstart[g + 1];
    float acc = 0.0f;
    for (int n = s0 + part; n < s1; n += 4) acc += x[n * 64 + j];
    red[t] = acc;
    __syncthreads();
    if (part == 0)
        c[j] = (red[j] + red[64 + j] + red[128 + j] + red[192 + j]) /
               fmaxf((float)(s1 - s0), 1.0f);
    __syncthreads();
    if (t < 128) {
        float av = bs[t];
#pragma unroll 8
        for (int k = 0; k < 64; ++k) av = fmaf(c[k], Ws[k * 128 + t], av);
        h1[t] = fmaxf(av, 0.0f);
    }
    __syncthreads();
    if (t < 128) {
        const float* W1p = (t < 64) ? Wbg1 : Weh1;
        const float* b1p = (t < 64) ? bbg1 : beh1;
        const float* W2p = (t < 64) ? Wbg2 : Weh2;
        float b2v = (t < 64) ? bbg2[0] : beh2[0];
        int ln = t & 63;
        float a2 = b1p[ln];
#pragma unroll 8
        for (int k = 0; k < 128; ++k) a2 = fmaf(h1[k], W1p[k * 64 + ln], a2);
        a2 = fmaxf(a2, 0.0f);
        float pr = a2 * W2p[ln];
#pragma unroll
        for (int off = 32; off > 0; off >>= 1) pr += __shfl_down(pr, off);
        if (ln == 0) out[(t < 64 ? 0 : n_graphs) + g] = pr + b2v;
    }
}

extern "C" void kernel_launch(void* const* d_in, const int* in_sizes, int n_in,
                              void* d_out, int out_size, void* d_ws, size_t ws_size,
                              hipStream_t stream) {
    const int*   x_ids = (const int*)d_in[0];
    const int*   eidx  = (const int*)d_in[1];
    const float* eattr = (const float*)d_in[2];
    const int*   batch = (const int*)d_in[3];
    const float* emb   = (const float*)d_in[4];
    const float* W1    = (const float*)d_in[5];
    const float* b1    = (const float*)d_in[6];
    const float* We    = (const float*)d_in[7];
    const float* be    = (const float*)d_in[8];
    const float* W2    = (const float*)d_in[9];
    const float* b2    = (const float*)d_in[10];
    const float* Ws_   = (const float*)d_in[11];
    const float* bs_   = (const float*)d_in[12];
    const float* Wbg1  = (const float*)d_in[13];
    const float* bbg1  = (const float*)d_in[14];
    const float* Wbg2  = (const float*)d_in[15];
    const float* bbg2  = (const float*)d_in[16];
    const float* Weh1  = (const float*)d_in[17];
    const float* beh1  = (const float*)d_in[18];
    const float* Weh2  = (const float*)d_in[19];
    const float* beh2  = (const float*)d_in[20];

    int n_nodes  = in_sizes[0];
    int n_edges  = in_sizes[2];
    int n_graphs = out_size / 2;
    const int* src = eidx;
    const int* dst = eidx + n_edges;
    int nbuck = (n_nodes + (1 << BSH) - 1) >> BSH;
    int nbc = (nbuck < 256 ? 256 : nbuck) + 4;   // bcursor alloc (>=256 for scat1)

    // base footprint
    size_t base_bytes =
        (size_t)n_nodes * 64 * sizeof(float)      // x
      + (size_t)n_nodes * 64 * sizeof(__half) * 2 // hA, hB
      + (size_t)n_edges * sizeof(int4)            // psort
      + (size_t)n_nodes * sizeof(int) * 2         // deg, cursor
      + (size_t)(n_nodes + 1) * sizeof(int)       // off
      + 256 * sizeof(int)                         // bsum
      + (size_t)(n_graphs + 1) * sizeof(int)      // gstart
      + (size_t)nbc * sizeof(int);                // bcursor
    size_t agg_bytes = (size_t)n_nodes * 64 * sizeof(float);
    size_t tmp_bytes = (size_t)n_edges * sizeof(int4);
    size_t aggtmp_bytes = agg_bytes > tmp_bytes ? agg_bytes : tmp_bytes;
    int use_split = (ws_size >= base_bytes + aggtmp_bytes + 1024) ? 1 : 0;

    char* p = (char*)d_ws;
    float* x     = (float*)p;   p += (size_t)n_nodes * 64 * sizeof(float);
    __half* hA   = (__half*)p;  p += (size_t)n_nodes * 64 * sizeof(__half);
    __half* hB   = (__half*)p;  p += (size_t)n_nodes * 64 * sizeof(__half);
    int4* psort  = (int4*)p;    p += (size_t)n_edges * sizeof(int4);
    int* deg     = (int*)p;     p += (size_t)n_nodes * sizeof(int);
    int* off_    = (int*)p;     p += (size_t)(n_nodes + 1) * sizeof(int);
    int* cursor  = (int*)p;     p += (size_t)n_nodes * sizeof(int);
    int* bsum    = (int*)p;     p += 256 * sizeof(int);
    int* gstart  = (int*)p;     p += (size_t)(n_graphs + 1) * sizeof(int);
    int* bcursor = (int*)p;     p += (size_t)nbc * sizeof(int);
    float* agg   = (float*)p;   // aliases tmp; only touched if use_split
    int4* tmp    = (int4*)p;
    float* out   = (float*)d_out;

    int nchunks = (n_nodes + 255) / 256;
    int nbE = (n_edges + 255) / 256;
    int nbN = (n_nodes + 255) / 256;
    int ntile = (n_nodes + 63) / 64;
    int nbS1 = (n_edges + 1023) / 1024;

    hipMemsetAsync(deg, 0, (size_t)n_nodes * sizeof(int), stream);
    k_pre<<<nbE, 256, 0, stream>>>(dst, deg, batch, gstart, x_ids, emb, W1, b1,
                                   x, hA, n_edges, n_nodes, n_graphs);
    k_scana<<<nchunks, 256, 0, stream>>>(deg, off_, bsum, n_nodes);
    k_scanb<<<1, 256, 0, stream>>>(bsum, nchunks);
    k_scanc<<<nbN, 256, 0, stream>>>(deg, bsum, off_, cursor, bcursor, n_nodes);

    if (use_split) {
        k_scat1<<<nbS1, 256, 0, stream>>>(src, dst, eattr, bcursor, tmp, n_edges);
        k_scat2<<<nbuck, 256, 0, stream>>>(tmp, off_, cursor, psort, n_nodes);
        // conv 0
        k_gather<<<4096, 256, 0, stream>>>(psort, off_, hA, We, be, agg, n_nodes);
        k_epi<<<ntile, 512, 0, stream>>>(agg, x, W2, b2,
                                         W1 + 4096, b1 + 64, hB, n_nodes, 1);
        // conv 1
        k_gather<<<4096, 256, 0, stream>>>(psort, off_, hB, We + 640, be + 64, agg, n_nodes);
        k_epi<<<ntile, 512, 0, stream>>>(agg, x, W2 + 4096, b2 + 64,
                                         W1 + 8192, b1 + 128, hA, n_nodes, 1);
        // conv 2
        k_gather<<<4096, 256, 0, stream>>>(psort, off_, hA, We + 1280, be + 128, agg, n_nodes);
        k_epi<<<ntile, 512, 0, stream>>>(agg, x, W2 + 8192, b2 + 128,
                                         nullptr, nullptr, nullptr, n_nodes, 0);
    } else {
        k_scatter<<<nbE, 256, 0, stream>>>(src, dst, eattr, cursor, psort, n_edges);
        k_conv<<<4096, 256, 0, stream>>>(psort, off_, hA, We, be, W2, b2,
                                         W1 + 4096, b1 + 64, x, hB, n_nodes, 1);
        k_conv<<<4096, 256, 0, stream>>>(psort, off_, hB, We + 640, be + 64,
                                         W2 + 4096, b2 + 64,
                                         W1 + 8192, b1 + 128, x, hA, n_nodes, 1);
        k_conv<<<4096, 256, 0, stream>>>(psort, off_, hA, We + 1280, be + 128,
                                         W2 + 8192, b2 + 128,
                                         nullptr, nullptr, x, nullptr, n_nodes, 0);
    }

    k_poolhead<<<n_graphs, 256, 0, stream>>>(x, gstart, Ws_, bs_, Wbg1, bbg1, Wbg2, bbg2,
                                             Weh1, beh1, Weh2, beh2, out, n_graphs);
}